// Round 11
// baseline (93.429 us; speedup 1.0000x reference)
//
#include <hip/hip_runtime.h>
#include <hip/hip_bf16.h>
#include <cstddef>

#define NE 65536
#define ND 256
#define NP 8
#define RBLK 64              // routing blocks
#define EPB (NE / RBLK)      // 1024 edges per routing block
#define TR 32                // rows per main tile
#define NBLK 256             // persistent-ish main blocks (1 per CU)
#define MAXCH 9              // max tiles per block chunk

typedef short bf16x8 __attribute__((ext_vector_type(8)));
typedef float f32x4  __attribute__((ext_vector_type(4)));
typedef const __attribute__((address_space(1))) unsigned int* gas_t;
typedef __attribute__((address_space(3))) unsigned int* las_t;

__device__ __forceinline__ unsigned short f2bf(float f) {
  unsigned int u = __float_as_uint(f);
  u += 0x7FFFu + ((u >> 16) & 1u);   // round-to-nearest-even
  return (unsigned short)(u >> 16);
}

// idx dtype sniff: odd 32-bit words all-zero <=> int64 (values < 8)
__device__ __forceinline__ int sniff_is32(const void* idxraw, int* lflag) {
  int tid = threadIdx.x;
  if (tid == 0) *lflag = 0;
  __syncthreads();
  const unsigned int* w = (const unsigned int*)idxraw;
  unsigned int val = w[((blockIdx.x & 63) * 256 + (tid & 255)) * 2 + 1];
  if (__any(val != 0) && (tid & 63) == 0) atomicOr(lflag, 1);
  __syncthreads();
  return *lflag;
}
__device__ __forceinline__ int load_idx(const void* idxraw, int is32, int e) {
  return is32 ? ((const int*)idxraw)[e] : (int)((const long long*)idxraw)[e];
}

// ---- phase 1: per-block LDS histogram ----
__global__ __launch_bounds__(256) void k_hist(const void* __restrict__ idxraw,
                                              int* __restrict__ counts) {
  __shared__ int h[NP];
  __shared__ int lflag;
  int tid = threadIdx.x;
  int is32 = sniff_is32(idxraw, &lflag);
  if (tid < NP) h[tid] = 0;
  __syncthreads();
  int base = blockIdx.x * EPB;
#pragma unroll
  for (int i = 0; i < EPB / 256; ++i) {
    int p = load_idx(idxraw, is32, base + tid + i * 256);
    atomicAdd(&h[p], 1);
  }
  __syncthreads();
  if (tid < NP) counts[blockIdx.x * NP + tid] = h[tid];
}

// ---- phase 2: totals, CSR offsets, 32-row tile prefix, per-block bases ----
__global__ __launch_bounds__(64) void k_scan(const int* __restrict__ counts,
                                             int* __restrict__ hdr,
                                             int* __restrict__ bases) {
  __shared__ int cnt[NP];
  __shared__ int off[NP + 1];
  int q = threadIdx.x;
  if (q < NP) {
    int s = 0;
    for (int b = 0; b < RBLK; ++b) s += counts[b * NP + q];
    cnt[q] = s;
  }
  __syncthreads();
  if (q == 0) {
    int o = 0, tt = 0;
    for (int p = 0; p < NP; ++p) {
      off[p] = o; hdr[p] = o; hdr[9 + p] = tt;
      o += cnt[p];
      tt += (cnt[p] + TR - 1) / TR;
    }
    off[NP] = o; hdr[NP] = o; hdr[9 + NP] = tt;
  }
  __syncthreads();
  if (q < NP) {
    int run = off[q];
    for (int b = 0; b < RBLK; ++b) {
      bases[b * NP + q] = run;
      run += counts[b * NP + q];
    }
  }
}

// ---- phase 3: CSR scatter with LDS cursors ----
__global__ __launch_bounds__(256) void k_scatter(const void* __restrict__ idxraw,
                                                 const int* __restrict__ bases,
                                                 int* __restrict__ perm) {
  __shared__ int cur[NP];
  __shared__ int lflag;
  int tid = threadIdx.x;
  int is32 = sniff_is32(idxraw, &lflag);
  if (tid < NP) cur[tid] = bases[blockIdx.x * NP + tid];
  __syncthreads();
  int base = blockIdx.x * EPB;
#pragma unroll
  for (int i = 0; i < EPB / 256; ++i) {
    int e = base + tid + i * 256;
    int p = load_idx(idxraw, is32, e);
    int slot = atomicAdd(&cur[p], 1);
    perm[slot] = e;
  }
}

// ---- prep: W_bil -> B-frag bf16 layout; v_p = b_lr[p] @ W_bil (fp32) ----
__global__ __launch_bounds__(256) void k_prep(const float* __restrict__ Wbil,
                                              const float* __restrict__ blr,
                                              unsigned short* __restrict__ WbT,
                                              float* __restrict__ v) {
  int b = blockIdx.x, t = threadIdx.x;
  if (b < 32) {
    int s = b * 256 + t;
    int kt = s >> 10, c = (s >> 6) & 15, l = s & 63;
    int col = c * 16 + (l & 15);
    int k0 = kt * 32 + (l >> 4) * 8;
    union { uint4 u; unsigned short h[8]; } uu;
#pragma unroll
    for (int j = 0; j < 8; ++j)
      uu.h[j] = f2bf(Wbil[(k0 + j) * ND + col]);
    *(uint4*)(WbT + (size_t)s * 8) = uu.u;
  } else {
    int p = b - 32;
    float s = 0.f;
    for (int k = 0; k < ND; ++k)
      s = fmaf(blr[p * ND + k], Wbil[k * ND + t], s);
    v[p * ND + t] = s;
  }
}

// ---- C_p = W_lr[p]^T @ W_bil  (bf16 MFMA), written in B-frag layout ----
__global__ __launch_bounds__(256) void k_cpre(const float* __restrict__ Wlr,
                                              const unsigned short* __restrict__ WbT,
                                              unsigned short* __restrict__ Cst) {
  __shared__ unsigned short aF[2048 * 8];
  int blk = blockIdx.x;
  int p = blk >> 2;
  int i0 = (blk & 3) * 64;
  int tid = threadIdx.x;
  const float* Wp = Wlr + (size_t)p * ND * ND;
#pragma unroll
  for (int it = 0; it < 8; ++it) {
    int s = tid + it * 256;
    int kt = s >> 8, r = (s >> 6) & 3, l = s & 63;
    int i = r * 16 + (l & 15);
    int k0 = kt * 32 + (l >> 4) * 8;
    union { uint4 u; unsigned short h[8]; } uu;
#pragma unroll
    for (int j = 0; j < 8; ++j)
      uu.h[j] = f2bf(Wp[(size_t)(k0 + j) * ND + i0 + i]);
    *(uint4*)(aF + (size_t)s * 8) = uu.u;
  }
  __syncthreads();
  int w = tid >> 6, l = tid & 63;
  f32x4 zero = {0.f, 0.f, 0.f, 0.f};
  f32x4 acc[16];
#pragma unroll
  for (int c = 0; c < 16; ++c) acc[c] = zero;
  for (int kt = 0; kt < 8; ++kt) {
    bf16x8 a = *(const bf16x8*)(aF + (size_t)((kt * 4 + w) * 64 + l) * 8);
#pragma unroll
    for (int c = 0; c < 16; ++c) {
      bf16x8 bb = *(const bf16x8*)(WbT + (size_t)((kt * 16 + c) * 64 + l) * 8);
      acc[c] = __builtin_amdgcn_mfma_f32_16x16x32_bf16(a, bb, acc[c], 0, 0, 0);
    }
  }
  unsigned short* Cp = Cst + (size_t)p * ND * ND;
#pragma unroll
  for (int c = 0; c < 16; ++c) {
#pragma unroll
    for (int q = 0; q < 4; ++q) {
      int i = i0 + w * 16 + ((l >> 4) * 4) + q;
      int j = c * 16 + (l & 15);
      int pos = ((i >> 5) * 16 + (j >> 4)) * 512 + (((i >> 3) & 3) * 16 + (j & 15)) * 8 + (i & 7);
      Cp[pos] = f2bf(acc[c][q]);
    }
  }
}

// ---- main v11: 256 blocks x 512 thr, 1/CU; each block owns ~8-9 contiguous
// CSR tiles. Double-buffered async staging via global_load_lds; counted
// s_waitcnt vmcnt(8) so the NEXT tile's loads stay in flight across the
// barrier and the entire compute phase (T3/T4). Raw s_barrier only (no
// __syncthreads in the loop — it would drain vmcnt(0) and kill the pipeline).
// B (Cst slice) cached in 64 VGPRs, reloaded only on expert change.
// LDS layout: 16B granules XOR'd by row&7 (pre-swizzled global source,
// swizzled reads) -> 2-way bank aliasing only (free).
__global__ __launch_bounds__(512, 2) void k_main(const float* __restrict__ zsrc,
                                                 const float* __restrict__ zdst,
                                                 const int* __restrict__ perm,
                                                 const int* __restrict__ hdr,
                                                 const unsigned short* __restrict__ Cst,
                                                 const float* __restrict__ v,
                                                 const float* __restrict__ bbil,
                                                 float* __restrict__ out) {
  __shared__ float zbuf[2][16384];       // 128 KiB: per buf [zs 32KB | zd 32KB]
  __shared__ float red[8][TR];           // 1 KiB
  __shared__ int eidsAll[MAXCH * TR];    // 1.125 KiB
  __shared__ int pExp[MAXCH], pNrow[MAXCH];
  __shared__ int shdr[18];
  int tid = threadIdx.x;
  if (tid < 18) shdr[tid] = hdr[tid];
  __syncthreads();
  int ntiles = shdr[17];
  int chunk = (ntiles + NBLK - 1) / NBLK;        // <= MAXCH
  int t0 = blockIdx.x * chunk;
  if (t0 >= ntiles) return;
  int t1 = t0 + chunk; if (t1 > ntiles) t1 = ntiles;
  for (int j = tid; j < (t1 - t0) * TR; j += 512) {
    int tl = j >> 5, tt = t0 + tl;
    int p = 0;
    while (p < NP - 1 && tt >= shdr[9 + p + 1]) ++p;
    int ebase = shdr[p] + (tt - shdr[9 + p]) * TR;
    int cend = shdr[p + 1];
    int r = j & 31;
    int re = ebase + r; if (re > cend - 1) re = cend - 1;
    eidsAll[j] = perm[re];
    if (r == 0) {
      pExp[tl] = p;
      int nr = cend - ebase; pNrow[tl] = nr > TR ? TR : nr;
    }
  }
  __syncthreads();   // one full sync before the pipeline starts

  int w = tid >> 6, l = tid & 63;
  int hh = l >> 4, rr = l & 15;
  float bb0 = bbil[0];

  // stage tile tt into buffer bsel: wave w stages rows w*4..w*4+3
#define STAGE(TT, BSEL)                                                          \
  {                                                                              \
    int _tl = (TT) - t0;                                                         \
    char* _zb = (char*)&zbuf[(BSEL)][0];                                         \
    _Pragma("unroll")                                                            \
    for (int _i = 0; _i < 4; ++_i) {                                             \
      int _row = w * 4 + _i;                                                     \
      int _e = eidsAll[_tl * TR + _row];                                         \
      unsigned _s = (unsigned)(_row & 7);                                        \
      unsigned _sf = (((unsigned)l ^ _s) << 2);                                  \
      const float* _gs = zsrc + (size_t)_e * ND + _sf;                           \
      const float* _gd = zdst + (size_t)_e * ND + _sf;                           \
      __builtin_amdgcn_global_load_lds((gas_t)(const void*)_gs,                  \
          (las_t)(void*)(_zb + _row * 1024), 16, 0, 0);                          \
      __builtin_amdgcn_global_load_lds((gas_t)(const void*)_gd,                  \
          (las_t)(void*)(_zb + 32768 + _row * 1024), 16, 0, 0);                  \
    }                                                                            \
  }

  STAGE(t0, 0);
  int bsel = 0;
  int curP = -1;
  bf16x8 bfr[2][8];
  float vloc[2];
  f32x4 zero = {0.f, 0.f, 0.f, 0.f};

  for (int tt = t0; tt < t1; ++tt) {
    int tl = tt - t0;
    if (tt + 1 < t1) {
      STAGE(tt + 1, bsel ^ 1);
      asm volatile("s_waitcnt vmcnt(8)" ::: "memory");   // tile tt resident; tt+1 in flight
    } else {
      asm volatile("s_waitcnt vmcnt(0)" ::: "memory");
    }
    __builtin_amdgcn_sched_barrier(0);
    __builtin_amdgcn_s_barrier();

    int p = pExp[tl];
    if (p != curP) {                      // rare: ~1-2 per block (contiguous CSR)
      curP = p;
      const unsigned short* Cp = Cst + (size_t)p * ND * ND;
#pragma unroll
      for (int cl = 0; cl < 2; ++cl) {
#pragma unroll
        for (int kt = 0; kt < 8; ++kt)
          bfr[cl][kt] = *(const bf16x8*)(Cp + (size_t)((kt * 16 + (w * 2 + cl)) * 64 + l) * 8);
        vloc[cl] = v[p * ND + (w * 2 + cl) * 16 + rr];
      }
    }

    const char* zs = (const char*)&zbuf[bsel][0];
    const char* zd = (const char*)&zbuf[bsel][8192];
    f32x4 acc[2][2];
#pragma unroll
    for (int sr = 0; sr < 2; ++sr)
#pragma unroll
      for (int cl = 0; cl < 2; ++cl) acc[sr][cl] = zero;

#pragma unroll
    for (int kt = 0; kt < 8; ++kt) {
      bf16x8 a[2];
#pragma unroll
      for (int sr = 0; sr < 2; ++sr) {
        int row = sr * 16 + rr;
        unsigned s = (unsigned)(row & 7);
        unsigned G0 = (unsigned)((kt * 4 + hh) * 2);
        float4 f0 = *(const float4*)(zs + row * 1024 + ((G0 ^ s) << 4));
        float4 f1 = *(const float4*)(zs + row * 1024 + (((G0 + 1) ^ s) << 4));
        union { bf16x8 vv; unsigned short h[8]; } ua;
        ua.h[0] = f2bf(f0.x); ua.h[1] = f2bf(f0.y); ua.h[2] = f2bf(f0.z); ua.h[3] = f2bf(f0.w);
        ua.h[4] = f2bf(f1.x); ua.h[5] = f2bf(f1.y); ua.h[6] = f2bf(f1.z); ua.h[7] = f2bf(f1.w);
        a[sr] = ua.vv;
      }
#pragma unroll
      for (int cl = 0; cl < 2; ++cl)
#pragma unroll
        for (int sr = 0; sr < 2; ++sr)
          acc[sr][cl] = __builtin_amdgcn_mfma_f32_16x16x32_bf16(a[sr], bfr[cl][kt], acc[sr][cl], 0, 0, 0);
    }

    // fused epilogue: fp32 z_dst from LDS; 4-lane-group reduce
#pragma unroll
    for (int sr = 0; sr < 2; ++sr) {
#pragma unroll
      for (int q = 0; q < 4; ++q) {
        int row = sr * 16 + hh * 4 + q;          // D-layout: col=l&15, row=(l>>4)*4+reg
        unsigned s = (unsigned)(row & 7);
        float sv = 0.f;
#pragma unroll
        for (int cl = 0; cl < 2; ++cl) {
          int col = (w * 2 + cl) * 16 + rr;
          unsigned byte = (unsigned)(row * 1024) +
                          ((((unsigned)(col >> 2) ^ s) << 4) | ((unsigned)(col & 3) << 2));
          float zv = *(const float*)(zd + byte);
          sv = fmaf(acc[sr][cl][q] + vloc[cl], zv, sv);
        }
        sv += __shfl_xor(sv, 1, 64);
        sv += __shfl_xor(sv, 2, 64);
        sv += __shfl_xor(sv, 4, 64);
        sv += __shfl_xor(sv, 8, 64);
        if (rr == 0) red[w][row] = sv;
      }
    }
    asm volatile("s_waitcnt lgkmcnt(0)" ::: "memory");   // red visible; vmcnt untouched
    __builtin_amdgcn_sched_barrier(0);
    __builtin_amdgcn_s_barrier();
    if (tid < TR && tid < pNrow[tl]) {
      float sc = bb0;
#pragma unroll
      for (int ww = 0; ww < 8; ++ww) sc += red[ww][tid];
      out[eidsAll[tl * TR + tid]] = sc;
    }
    bsel ^= 1;
  }
#undef STAGE
}

extern "C" void kernel_launch(void* const* d_in, const int* in_sizes, int n_in,
                              void* d_out, int out_size, void* d_ws, size_t ws_size,
                              hipStream_t stream) {
  // setup_inputs() dict order: z_src, z_dst, W_lr, b_lr, W_bil, b_bil, lr_pair_idx
  const float* zsrc = (const float*)d_in[0];
  const float* zdst = (const float*)d_in[1];
  const float* Wlr  = (const float*)d_in[2];
  const float* blr  = (const float*)d_in[3];
  const float* Wbil = (const float*)d_in[4];
  const float* bbil = (const float*)d_in[5];
  const void*  idx  = (const void*)d_in[6];
  float* out = (float*)d_out;

  char* ws = (char*)d_ws;
  int* hdr    = (int*)ws;                                  // 72 B
  int* counts = (int*)(ws + 4096);                         // 2 KiB
  int* bases  = (int*)(ws + 8192);                         // 2 KiB
  int* perm   = (int*)(ws + 16384);                        // 256 KiB (CSR)
  unsigned short* WbT = (unsigned short*)(ws + 16384 + (size_t)NE * 4);            // 128 KiB
  float* v = (float*)(ws + 16384 + (size_t)NE * 4 + 131072);                       // 8 KiB
  unsigned short* Cst = (unsigned short*)(ws + 16384 + (size_t)NE * 4 + 131072 + 8192); // 1 MiB

  k_prep<<<40, 256, 0, stream>>>(Wbil, blr, WbT, v);
  k_hist<<<RBLK, 256, 0, stream>>>(idx, counts);
  k_scan<<<1, 64, 0, stream>>>(counts, hdr, bases);
  k_scatter<<<RBLK, 256, 0, stream>>>(idx, bases, perm);
  k_cpre<<<32, 256, 0, stream>>>(Wlr, WbT, Cst);
  k_main<<<NBLK, 512, 0, stream>>>(zsrc, zdst, perm, hdr, Cst, v, bbil, out);
}

// Round 12
// 77.897 us; speedup vs baseline: 1.1994x; 1.1994x over previous
//
#include <hip/hip_runtime.h>
#include <hip/hip_bf16.h>
#include <cstddef>

#define NE 65536
#define ND 256
#define NP 8
#define RBLK 64              // hist/scatter blocks
#define EPB (NE / RBLK)      // 1024 edges per routing block
#define TR 32                // rows per main tile
#define MAXT 2056            // max tiles: 2048 + 8

typedef short bf16x8 __attribute__((ext_vector_type(8)));
typedef float f32x4  __attribute__((ext_vector_type(4)));

__device__ __forceinline__ unsigned short f2bf(float f) {
  unsigned int u = __float_as_uint(f);
  u += 0x7FFFu + ((u >> 16) & 1u);   // round-to-nearest-even
  return (unsigned short)(u >> 16);
}
__device__ __forceinline__ float bf2f(unsigned short h) {
  return __uint_as_float(((unsigned int)h) << 16);
}
__device__ __forceinline__ int load_idx(const void* idxraw, int is32, int e) {
  return is32 ? ((const int*)idxraw)[e] : (int)((const long long*)idxraw)[e];
}
// idx dtype sniff: odd 32-bit words all-zero <=> int64 (values < 8)
__device__ __forceinline__ int sniff_is32(const void* idxraw, int* lflag, int bsel) {
  int tid = threadIdx.x;
  if (tid == 0) *lflag = 0;
  __syncthreads();
  const unsigned int* w = (const unsigned int*)idxraw;
  unsigned int val = w[((bsel & 63) * 256 + tid) * 2 + 1];
  if (__any(val != 0) && (tid & 63) == 0) atomicOr(lflag, 1);
  __syncthreads();
  return *lflag;
}

// ---- fused prep (W_bil frag + v) and per-block histogram ----
__global__ __launch_bounds__(256) void k_pre0(const float* __restrict__ Wbil,
                                              const float* __restrict__ blr,
                                              const void* __restrict__ idxraw,
                                              unsigned short* __restrict__ WbT,
                                              float* __restrict__ v,
                                              int* __restrict__ counts) {
  int b = blockIdx.x, t = threadIdx.x;
  if (b < 32) {
    int s = b * 256 + t;
    int kt = s >> 10, c = (s >> 6) & 15, l = s & 63;
    int col = c * 16 + (l & 15);
    int k0 = kt * 32 + (l >> 4) * 8;
    union { uint4 u; unsigned short h[8]; } uu;
#pragma unroll
    for (int j = 0; j < 8; ++j)
      uu.h[j] = f2bf(Wbil[(k0 + j) * ND + col]);
    *(uint4*)(WbT + (size_t)s * 8) = uu.u;
  } else if (b < 40) {
    int p = b - 32;
    float s = 0.f;
    for (int k = 0; k < ND; ++k)
      s = fmaf(blr[p * ND + k], Wbil[k * ND + t], s);
    v[p * ND + t] = s;
  } else {
    __shared__ int h[NP];
    __shared__ int lflag;
    int hb = b - 40;
    int is32 = sniff_is32(idxraw, &lflag, hb);
    if (t < NP) h[t] = 0;
    __syncthreads();
    int base = hb * EPB;
#pragma unroll
    for (int i = 0; i < EPB / 256; ++i) {
      int p = load_idx(idxraw, is32, base + t + i * 256);
      atomicAdd(&h[p], 1);
    }
    __syncthreads();
    if (t < NP) counts[hb * NP + t] = h[t];
  }
}

// ---- scan: totals, CSR offsets, 32-row tile prefix, per-block bases ----
__global__ __launch_bounds__(64) void k_scan(const int* __restrict__ counts,
                                             int* __restrict__ hdr,
                                             int* __restrict__ bases) {
  __shared__ int cnt[NP];
  __shared__ int off[NP + 1];
  int q = threadIdx.x;
  if (q < NP) {
    int s = 0;
    for (int b = 0; b < RBLK; ++b) s += counts[b * NP + q];
    cnt[q] = s;
  }
  __syncthreads();
  if (q == 0) {
    int o = 0, tt = 0;
    for (int p = 0; p < NP; ++p) {
      off[p] = o; hdr[p] = o; hdr[9 + p] = tt;
      o += cnt[p];
      tt += (cnt[p] + TR - 1) / TR;
    }
    off[NP] = o; hdr[NP] = o; hdr[9 + NP] = tt;
  }
  __syncthreads();
  if (q < NP) {
    int run = off[q];
    for (int b = 0; b < RBLK; ++b) {
      bases[b * NP + q] = run;
      run += counts[b * NP + q];
    }
  }
}

// ---- fused CSR scatter + C_p precompute ----
__global__ __launch_bounds__(256) void k_sc2(const void* __restrict__ idxraw,
                                             const int* __restrict__ bases,
                                             int* __restrict__ perm,
                                             const float* __restrict__ Wlr,
                                             const unsigned short* __restrict__ WbT,
                                             unsigned short* __restrict__ Cst) {
  __shared__ unsigned short aF[2048 * 8];   // used by cpre half only
  int b = blockIdx.x, tid = threadIdx.x;
  if (b < 64) {
    __shared__ int cur[NP];
    __shared__ int lflag;
    int is32 = sniff_is32(idxraw, &lflag, b);
    if (tid < NP) cur[tid] = bases[b * NP + tid];
    __syncthreads();
    int base = b * EPB;
#pragma unroll
    for (int i = 0; i < EPB / 256; ++i) {
      int e = base + tid + i * 256;
      int p = load_idx(idxraw, is32, e);
      int slot = atomicAdd(&cur[p], 1);
      perm[slot] = e;
    }
    return;
  }
  int blk = b - 64;
  int p = blk >> 2;
  int i0 = (blk & 3) * 64;
  const float* Wp = Wlr + (size_t)p * ND * ND;
#pragma unroll
  for (int it = 0; it < 8; ++it) {
    int s = tid + it * 256;
    int kt = s >> 8, r = (s >> 6) & 3, l = s & 63;
    int i = r * 16 + (l & 15);
    int k0 = kt * 32 + (l >> 4) * 8;
    union { uint4 u; unsigned short h[8]; } uu;
#pragma unroll
    for (int j = 0; j < 8; ++j)
      uu.h[j] = f2bf(Wp[(size_t)(k0 + j) * ND + i0 + i]);
    *(uint4*)(aF + (size_t)s * 8) = uu.u;
  }
  __syncthreads();
  int w = tid >> 6, l = tid & 63;
  f32x4 zero = {0.f, 0.f, 0.f, 0.f};
  f32x4 acc[16];
#pragma unroll
  for (int c = 0; c < 16; ++c) acc[c] = zero;
  for (int kt = 0; kt < 8; ++kt) {
    bf16x8 a = *(const bf16x8*)(aF + (size_t)((kt * 4 + w) * 64 + l) * 8);
#pragma unroll
    for (int c = 0; c < 16; ++c) {
      bf16x8 bb = *(const bf16x8*)(WbT + (size_t)((kt * 16 + c) * 64 + l) * 8);
      acc[c] = __builtin_amdgcn_mfma_f32_16x16x32_bf16(a, bb, acc[c], 0, 0, 0);
    }
  }
  unsigned short* Cp = Cst + (size_t)p * ND * ND;
#pragma unroll
  for (int c = 0; c < 16; ++c) {
#pragma unroll
    for (int q = 0; q < 4; ++q) {
      int i = i0 + w * 16 + ((l >> 4) * 4) + q;
      int j = c * 16 + (l & 15);
      int pos = ((i >> 5) * 16 + (j >> 4)) * 512 + (((i >> 3) & 3) * 16 + (j & 15)) * 8 + (i & 7);
      Cp[pos] = f2bf(acc[c][q]);
    }
  }
}

// ---- main v12: one 32-row CSR tile per block; 512 thr (8 waves x 32 cols);
// launch_bounds(512,8) -> VGPR<=64 -> 4 blocks/CU = 32 waves/CU. Pure TLP:
// no intra-block pipeline; independent blocks interleave staging/compute on
// the CU, maximizing outstanding scattered-row reads (the R3-R11 wall).
// z staged ONCE as bf16 (zs in MFMA A-frag layout + XOR swizzle; zd row-major
// + XOR), so the GEMM loop has zero conversions and small LDS (34 KB).
__global__ __launch_bounds__(512, 8) void k_main(const float* __restrict__ zsrc,
                                                 const float* __restrict__ zdst,
                                                 const int* __restrict__ perm,
                                                 const int* __restrict__ hdr,
                                                 const unsigned short* __restrict__ Cst,
                                                 const float* __restrict__ v,
                                                 const float* __restrict__ bbil,
                                                 float* __restrict__ out) {
  __shared__ unsigned short zs[8192];    // 16 KiB: A-frag layout, granule-XOR
  __shared__ unsigned short zd[8192];    // 16 KiB: row-major 512B/row, XOR
  __shared__ float red[8][TR];           // 1 KiB
  __shared__ int eids[TR];
  __shared__ int shdr[18];
  int tid = threadIdx.x;
  if (tid < 18) shdr[tid] = hdr[tid];
  __syncthreads();
  int bid = blockIdx.x;
  if (bid >= shdr[9 + NP]) return;
  int p = 0;
  while (p < NP - 1 && bid >= shdr[9 + p + 1]) ++p;
  int t = bid - shdr[9 + p];
  int cnt = shdr[p + 1] - shdr[p];
  int ebase = shdr[p] + t * TR;
  int nrow = cnt - t * TR; if (nrow > TR) nrow = TR;
  if (tid < TR) eids[tid] = perm[ebase + (tid < nrow ? tid : nrow - 1)];
  __syncthreads();
  int w = tid >> 6, l = tid & 63;
  int hh = l >> 4, rr = l & 15;

  // ---- staging: wave w stages rows w*4..w*4+3; lane l covers cols [4l,4l+4)
  int kt0 = l >> 3, q0 = (l >> 1) & 3, par0 = l & 1;
#pragma unroll
  for (int i = 0; i < 4; ++i) {
    int row = w * 4 + i;
    int e = eids[row];
    float4 fs = *(const float4*)(zsrc + (size_t)e * ND + l * 4);
    float4 fd = *(const float4*)(zdst + (size_t)e * ND + l * 4);
    union { unsigned long long u; unsigned short h[4]; } us, ud;
    us.h[0] = f2bf(fs.x); us.h[1] = f2bf(fs.y); us.h[2] = f2bf(fs.z); us.h[3] = f2bf(fs.w);
    ud.h[0] = f2bf(fd.x); ud.h[1] = f2bf(fd.y); ud.h[2] = f2bf(fd.z); ud.h[3] = f2bf(fd.w);
    // zs A-frag: granule g=(kt*2+sr)*64 + (row&15) + 16*q; swz g^=((g>>6)&7)<<1
    unsigned g = (unsigned)((kt0 * 2 + (row >> 4)) * 64 + (row & 15) + 16 * q0);
    g ^= ((g >> 6) & 7u) << 1;
    *(unsigned long long*)((char*)zs + g * 16 + par0 * 8) = us.u;
    // zd row-major: byte = row*512 + l*8, XOR ((row&7)<<5)
    *(unsigned long long*)((char*)zd + ((unsigned)(row * 512 + l * 8) ^ (((unsigned)row & 7u) << 5))) = ud.u;
  }
  __syncthreads();

  // ---- GEMM: wave w covers col-tiles {2w, 2w+1}; 2 row-strips; B from L2 ----
  const unsigned short* Cp = Cst + (size_t)p * ND * ND;
  f32x4 zero = {0.f, 0.f, 0.f, 0.f};
  f32x4 acc[2][2];
#pragma unroll
  for (int sr = 0; sr < 2; ++sr)
#pragma unroll
    for (int cl = 0; cl < 2; ++cl) acc[sr][cl] = zero;
#pragma unroll
  for (int kt = 0; kt < 8; ++kt) {
    bf16x8 a[2];
#pragma unroll
    for (int sr = 0; sr < 2; ++sr) {
      unsigned g = (unsigned)((kt * 2 + sr) * 64 + l);
      g ^= ((g >> 6) & 7u) << 1;
      a[sr] = *(const bf16x8*)((const char*)zs + g * 16);
    }
#pragma unroll
    for (int cl = 0; cl < 2; ++cl) {
      bf16x8 bb = *(const bf16x8*)(Cp + (size_t)((kt * 16 + (w * 2 + cl)) * 64 + l) * 8);
#pragma unroll
      for (int sr = 0; sr < 2; ++sr)
        acc[sr][cl] = __builtin_amdgcn_mfma_f32_16x16x32_bf16(a[sr], bb, acc[sr][cl], 0, 0, 0);
    }
  }

  // ---- fused epilogue: bf16 z_dst from LDS; 4-lane-group reduce ----
  float vloc[2];
#pragma unroll
  for (int cl = 0; cl < 2; ++cl)
    vloc[cl] = v[p * ND + (w * 2 + cl) * 16 + rr];
#pragma unroll
  for (int sr = 0; sr < 2; ++sr) {
#pragma unroll
    for (int q = 0; q < 4; ++q) {
      int row = sr * 16 + hh * 4 + q;          // D-layout: col=l&15, row=(l>>4)*4+reg
      unsigned swz = ((unsigned)row & 7u) << 5;
      float sv = 0.f;
#pragma unroll
      for (int cl = 0; cl < 2; ++cl) {
        int col = (w * 2 + cl) * 16 + rr;
        unsigned byte = ((unsigned)(row * 512 + col * 2)) ^ swz;
        sv = fmaf(acc[sr][cl][q] + vloc[cl], bf2f(*(const unsigned short*)((const char*)zd + byte)), sv);
      }
      sv += __shfl_xor(sv, 1, 64);
      sv += __shfl_xor(sv, 2, 64);
      sv += __shfl_xor(sv, 4, 64);
      sv += __shfl_xor(sv, 8, 64);
      if (rr == 0) red[w][row] = sv;
    }
  }
  __syncthreads();
  if (tid < TR && tid < nrow) {
    float sc = bbil[0];
#pragma unroll
    for (int ww = 0; ww < 8; ++ww) sc += red[ww][tid];
    out[eids[tid]] = sc;
  }
}

extern "C" void kernel_launch(void* const* d_in, const int* in_sizes, int n_in,
                              void* d_out, int out_size, void* d_ws, size_t ws_size,
                              hipStream_t stream) {
  // setup_inputs() dict order: z_src, z_dst, W_lr, b_lr, W_bil, b_bil, lr_pair_idx
  const float* zsrc = (const float*)d_in[0];
  const float* zdst = (const float*)d_in[1];
  const float* Wlr  = (const float*)d_in[2];
  const float* blr  = (const float*)d_in[3];
  const float* Wbil = (const float*)d_in[4];
  const float* bbil = (const float*)d_in[5];
  const void*  idx  = (const void*)d_in[6];
  float* out = (float*)d_out;

  char* ws = (char*)d_ws;
  int* hdr    = (int*)ws;                                  // 72 B
  int* counts = (int*)(ws + 4096);                         // 2 KiB
  int* bases  = (int*)(ws + 8192);                         // 2 KiB
  int* perm   = (int*)(ws + 16384);                        // 256 KiB (CSR)
  unsigned short* WbT = (unsigned short*)(ws + 16384 + (size_t)NE * 4);            // 128 KiB
  float* v = (float*)(ws + 16384 + (size_t)NE * 4 + 131072);                       // 8 KiB
  unsigned short* Cst = (unsigned short*)(ws + 16384 + (size_t)NE * 4 + 131072 + 8192); // 1 MiB

  k_pre0<<<104, 256, 0, stream>>>(Wbil, blr, idx, WbT, v, counts);
  k_scan<<<1, 64, 0, stream>>>(counts, hdr, bases);
  k_sc2<<<96, 256, 0, stream>>>(idx, bases, perm, Wlr, WbT, Cst);
  k_main<<<MAXT, 512, 0, stream>>>(zsrc, zdst, perm, hdr, Cst, v, bbil, out);
}